// Round 20
// baseline (695.304 us; speedup 1.0000x reference)
//
#include <hip/hip_runtime.h>
#include <math.h>

// ---------------------------------------------------------------------------
// STaRNet forward, fully fused fp32 pipeline.
//
//  k_prep : split across 9 small blocks (8 tap-blocks + 1 M-fold block) to
//           remove the single-block serial latency (R19: ~15-20us).
//  k_main : R13 structure + v_pk_fma_f32 (inline asm, "s" weight source:
//           VOP3P allows 1 SGPR-pair read) for conv taps (336->168 instr/g)
//           and y-accum (576->288 instr/g).  Same op order -> same absmax.
//  k_eig  : R12 structure, NSWEEP 4 (absmax 2^-7 = 82% of threshold, floor).
//           Jacobi measured at 97% of the CU LDS-issue bound (432 instr x
//           5.8cyc vs 2570 cyc/round) -> structurally done.
// ---------------------------------------------------------------------------

typedef __attribute__((ext_vector_type(2))) float v2f;
typedef __attribute__((ext_vector_type(4))) float v4f;

#define NSWEEP 4

// ws float offsets
#define WS_M      0         // 50*22
#define WS_BIASF  1100      // 50
#define WS_WTF    1152      // 50*336 compact taps
#define WS_BT     17952     // 450
#define WS_HPART  18432     // 512
#define WS_Y      32768     // 128*64*1001

// D = S0*S1 + D, packed 2xfp32.  S0 is wave-uniform -> SGPR pair (VOP3P
// permits one scalar source); S2/D tied accumulator in VGPRs.
__device__ __forceinline__ void pk_fma(v2f& acc, v2f ws, v2f hv) {
    asm("v_pk_fma_f32 %0, %1, %2, %0" : "+v"(acc) : "s"(ws), "v"(hv));
}

__global__ void k_prep(
    const float* __restrict__ ws0, const float* __restrict__ ws1, const float* __restrict__ ws2,
    const float* __restrict__ bsg, const float* __restrict__ bsb, const float* __restrict__ bsm, const float* __restrict__ bsv,
    const float* __restrict__ wf,
    const float* __restrict__ bfg, const float* __restrict__ bfb, const float* __restrict__ bfm, const float* __restrict__ bfv,
    const float* __restrict__ wt0, const float* __restrict__ wt1, const float* __restrict__ wt2,
    const float* __restrict__ btg, const float* __restrict__ btb, const float* __restrict__ btm, const float* __restrict__ btv,
    float* __restrict__ wsf)
{
    int tid = threadIdx.x;
    int blk = blockIdx.x;
    if (blk < 8) {
        int c = blk * 64 + tid;   // 8 blocks x 64 threads cover 450 channels
        if (c < 450) {
            int i = c / 150, o = c % 150;
            int g = o / 3,   jr = o % 3;
            int k = (i == 0) ? 64 : ((i == 1) ? 32 : 16);
            float ga = btg[i*150 + o], bb = btb[i*150 + o];
            float mm = btm[i*150 + o], vv = btv[i*150 + o];
            float s = ga * rsqrtf(vv + 1e-5f);
            wsf[WS_BT + c] = bb - s * mm;
            int base = g*336 + ((i == 0) ? jr*64 : (i == 1) ? 192 + jr*32 : 288 + jr*16);
            const float* wsrc = (i == 0) ? wt0 : ((i == 1) ? wt1 : wt2);
            float* dst = wsf + WS_WTF + base;
            for (int t = 0; t < k; ++t) dst[t] = s * wsrc[o*k + t];
        }
    } else {
        if (tid < 50) {
            int f = tid;
            float sf = bfg[f] * rsqrtf(bfv[f] + 1e-5f);
            float row[22];
            for (int c = 0; c < 22; ++c) row[c] = 0.f;
            float bacc = 0.f;
            for (int j = 0; j < 60; ++j) {
                int i, k, j0; const float* wsp;
                if (j < 22)      { i = 0; k = 1; j0 = j;      wsp = ws0; }
                else if (j < 42) { i = 1; k = 3; j0 = j - 22; wsp = ws1; }
                else             { i = 2; k = 5; j0 = j - 42; wsp = ws2; }
                float si = bsg[i] * rsqrtf(bsv[i] + 1e-5f);
                float bi = bsb[i] - si * bsm[i];
                float wfj = wf[f*60 + j];
                for (int d = 0; d < k; ++d) row[j0 + d] += wfj * si * wsp[d];
                bacc += wfj * bi;
            }
            for (int c = 0; c < 22; ++c) wsf[WS_M + f*22 + c] = sf * row[c];
            wsf[WS_BIASF + f] = sf * (bacc - bfm[f]) + bfb[f];
        }
    }
}

// ---------------------------------------------------------------------------
__global__ __launch_bounds__(256) void k_main(
    const float* __restrict__ x, const float* __restrict__ wsf,
    const float* __restrict__ Wmap, float* __restrict__ y,
    float* __restrict__ hpart)
{
    const int b    = blockIdx.x >> 2;
    const int tile = blockIdx.x & 3;
    const int t0   = tile * 256;
    const int tid  = threadIdx.x;

    __shared__ float xt[25][320];   // xf half-tile (31.25 KB -> 5 blocks/CU)
    __shared__ float wred[4];

    const float* Mg    = wsf + WS_M;
    const float* biasf = wsf + WS_BIASF;
    const float* wtf   = wsf + WS_WTF;
    const float* bt    = wsf + WS_BT;

    const int t = t0 + tid;
    const bool act = (t <= 1000);
    v2f yv2[32];   // pair m: {y[2m], y[2m+1]}
    #pragma unroll
    for (int m = 0; m < 32; ++m) yv2[m] = (v2f){0.f, 0.f};
    float hsq = 0.f;

    for (int ph = 0; ph < 2; ++ph) {
        const int gbase = 25 * ph;
        if (ph) __syncthreads();   // prev-phase conv reads done before restage

        // ---- stage xf rows [gbase, gbase+25) ----
        for (int col = tid; col < 320; col += 256) {
            int tx = t0 + col - 32;
            if (tx >= 0 && tx < 1000) {
                float xv[22];
                #pragma unroll
                for (int c = 0; c < 22; ++c) xv[c] = x[(b*22 + c)*1000 + tx];
                for (int gl = 0; gl < 25; ++gl) {
                    int g = gbase + gl;
                    float a = biasf[g];
                    #pragma unroll
                    for (int c = 0; c < 22; ++c) a += Mg[g*22 + c] * xv[c];
                    xt[gl][col] = a;
                }
            } else {
                for (int gl = 0; gl < 25; ++gl) xt[gl][col] = 0.f;
            }
        }
        __syncthreads();

        // ---- conv + y-accum for these 25 g (packed fp32) ----
        if (act) {
            for (int gl = 0; gl < 25; ++gl) {
                const int g = gbase + gl;
                const float* xb = &xt[gl][tid];
                const float* wg = wtf + g * 336;
                v2f h2[9];
                #pragma unroll
                for (int j = 0; j < 9; ++j) h2[j] = (v2f){0.f, 0.f};
                #pragma unroll
                for (int tau = 0; tau < 64; tau += 2) {
                    v2f xv = (v2f){xb[tau], xb[tau+1]};
                    pk_fma(h2[0], *(const v2f*)(wg + tau),       xv);
                    pk_fma(h2[1], *(const v2f*)(wg + 64 + tau),  xv);
                    pk_fma(h2[2], *(const v2f*)(wg + 128 + tau), xv);
                    if (tau >= 16 && tau < 48) {
                        int u = tau - 16;
                        pk_fma(h2[3], *(const v2f*)(wg + 192 + u), xv);
                        pk_fma(h2[4], *(const v2f*)(wg + 224 + u), xv);
                        pk_fma(h2[5], *(const v2f*)(wg + 256 + u), xv);
                    }
                    if (tau >= 24 && tau < 40) {
                        int u = tau - 24;
                        pk_fma(h2[6], *(const v2f*)(wg + 288 + u), xv);
                        pk_fma(h2[7], *(const v2f*)(wg + 304 + u), xv);
                        pk_fma(h2[8], *(const v2f*)(wg + 320 + u), xv);
                    }
                }
                #pragma unroll
                for (int j = 0; j < 9; ++j) {
                    int c = (j < 3) ? (3*g + j)
                          : (j < 6) ? (150 + 3*g + (j - 3))
                                    : (300 + 3*g + (j - 6));
                    float hv = h2[j].x + h2[j].y + bt[c];
                    hsq += hv * hv;
                    const v2f* wr2 = (const v2f*)(Wmap + c * 64);  // wave-uniform
                    v2f hv2 = (v2f){hv, hv};
                    #pragma unroll
                    for (int m = 0; m < 32; ++m) pk_fma(yv2[m], wr2[m], hv2);
                }
            }
        }
    }

    if (act) {
        #pragma unroll
        for (int k = 0; k < 32; ++k) {
            y[(b*64 + 2*k    )*1001 + t] = yv2[k].x;
            y[(b*64 + 2*k + 1)*1001 + t] = yv2[k].y;
        }
    }

    for (int off = 32; off > 0; off >>= 1) hsq += __shfl_down(hsq, off, 64);
    int wid = tid >> 6, lane = tid & 63;
    if (lane == 0) wred[wid] = hsq;
    __syncthreads();
    if (tid == 0) hpart[blockIdx.x] = wred[0] + wred[1] + wred[2] + wred[3];
}

// ---------------------------------------------------------------------------
// pair schedule: round rr, pair j: j==0 -> (63, rr); else
// p=(rr+j)%63, q=(rr+63-j)%63. All pairs disjoint within a round.
__device__ __forceinline__ void pair_pq(int rr, int j, int& p, int& q) {
    if (j == 0) { p = 63; q = rr; }
    else {
        int a = rr + j;       if (a >= 63) a -= 63;
        int c = rr + 63 - j;  if (c >= 63) c -= 63;
        p = a; q = c;
    }
}

union SMu {
    float yt[64][129];                               // syrk staging (33024 B)
    struct { float A[64][65]; float V[64][65]; } j;  // Jacobi (33280 B)
};

__global__ __launch_bounds__(1024) void k_eig(
    const float* __restrict__ y, const float* __restrict__ hpart,
    const float* __restrict__ fcw, const float* __restrict__ fcb,
    float* __restrict__ out)
{
    const int b    = blockIdx.x;
    const int tid  = threadIdx.x;
    const int w    = tid >> 6;     // wave 0..15
    const int lane = tid & 63;

    __shared__ SMu U;
    __shared__ float le[64];
    __shared__ float wred2[16];

    // ---- syrk: acc = y y^T; staging by all 16 waves, MACs on first 256 ----
    const int mg = tid >> 4, ng = tid & 15;       // valid for tid<256
    const int m0 = mg * 4,  n0 = ng * 4;
    float acc[16];
    #pragma unroll
    for (int i = 0; i < 16; ++i) acc[i] = 0.f;
    for (int tile = 0; tile < 8; ++tile) {
        for (int idx = tid; idx < 64*128; idx += 1024) {
            int row = idx >> 7, col = idx & 127;
            int tg = tile * 128 + col;
            U.yt[row][col] = (tg <= 1000) ? y[(b*64 + row)*1001 + tg] : 0.f;
        }
        __syncthreads();
        if (tid < 256) {
            for (int tt = 0; tt < 128; ++tt) {
                float ym[4], yn[4];
                #pragma unroll
                for (int i = 0; i < 4; ++i) ym[i] = U.yt[m0 + i][tt];
                #pragma unroll
                for (int j = 0; j < 4; ++j) yn[j] = U.yt[n0 + j][tt];
                #pragma unroll
                for (int i = 0; i < 4; ++i)
                    #pragma unroll
                    for (int j = 0; j < 4; ++j) acc[i*4 + j] += ym[i] * yn[j];
            }
        }
        __syncthreads();
    }
    if (tid < 256) {
        float hs = hpart[b*4] + hpart[b*4+1] + hpart[b*4+2] + hpart[b*4+3];
        float mu = hs / (999.f * 450.f);
        #pragma unroll
        for (int i = 0; i < 4; ++i)
            #pragma unroll
            for (int j = 0; j < 4; ++j) {
                int mm = m0 + i, nn = n0 + j;
                U.j.A[mm][nn] = acc[i*4 + j] * (0.95f / 999.f)
                              + ((mm == nn) ? 0.05f * mu : 0.f);
                U.j.V[mm][nn] = (mm == nn) ? 1.f : 0.f;
            }
    }
    __syncthreads();

    // ---- parallel cyclic Jacobi: 16 waves x 2 pairs, conflict-free b32 ----
    for (int sweep = 0; sweep < NSWEEP; ++sweep)
    for (int rr = 0; rr < 63; ++rr) {
        float cp, sp;
        {
            int jj = w + ((lane & 1) << 4);
            int p, q; pair_pq(rr, jj, p, q);
            float app = U.j.A[p][p], aqq = U.j.A[q][q], apq = U.j.A[p][q];
            bool z = (fabsf(apq) <= 1e-30f);
            float apqs = z ? 1.f : apq;
            float tau = (aqq - app) * __builtin_amdgcn_rcpf(2.f * apqs);
            float tt = copysignf(1.f, tau) / (fabsf(tau) + sqrtf(1.f + tau*tau));
            float c = rsqrtf(1.f + tt*tt);
            float s = tt * c;
            cp = z ? 1.f : c;
            sp = z ? 0.f : s;
        }
        float c0 = __shfl(cp, 0, 64), s0 = __shfl(sp, 0, 64);
        float c1 = __shfl(cp, 1, 64), s1 = __shfl(sp, 1, 64);
        int p0, q0, p1, q1;
        pair_pq(rr, w,      p0, q0);
        pair_pq(rr, w + 16, p1, q1);

        // col phase: batched loads, rotate, batched stores (A and V)
        float a0p = U.j.A[lane][p0], a0q = U.j.A[lane][q0];
        float a1p = U.j.A[lane][p1], a1q = U.j.A[lane][q1];
        float v0p = U.j.V[lane][p0], v0q = U.j.V[lane][q0];
        float v1p = U.j.V[lane][p1], v1q = U.j.V[lane][q1];
        U.j.A[lane][p0] = c0*a0p - s0*a0q;
        U.j.A[lane][q0] = s0*a0p + c0*a0q;
        U.j.A[lane][p1] = c1*a1p - s1*a1q;
        U.j.A[lane][q1] = s1*a1p + c1*a1q;
        U.j.V[lane][p0] = c0*v0p - s0*v0q;
        U.j.V[lane][q0] = s0*v0p + c0*v0q;
        U.j.V[lane][p1] = c1*v1p - s1*v1q;
        U.j.V[lane][q1] = s1*v1p + c1*v1q;
        __syncthreads();

        // row phase (A only)
        float r0p = U.j.A[p0][lane], r0q = U.j.A[q0][lane];
        float r1p = U.j.A[p1][lane], r1q = U.j.A[q1][lane];
        U.j.A[p0][lane] = c0*r0p - s0*r0q;
        U.j.A[q0][lane] = s0*r0p + c0*r0q;
        U.j.A[p1][lane] = c1*r1p - s1*r1q;
        U.j.A[q1][lane] = s1*r1p + c1*r1q;
        __syncthreads();
    }

    // ---- log-eig reconstruction + FC (first 256 threads) ----
    if (tid < 64) le[tid] = logf(fmaxf(U.j.A[tid][tid], 1e-6f));
    __syncthreads();

    if (tid < 256) {
        float lm[16];
        #pragma unroll
        for (int i = 0; i < 16; ++i) lm[i] = 0.f;
        for (int k = 0; k < 64; ++k) {
            float l = le[k];
            float vm[4], vn[4];
            #pragma unroll
            for (int i = 0; i < 4; ++i) vm[i] = U.j.V[m0 + i][k] * l;
            #pragma unroll
            for (int j = 0; j < 4; ++j) vn[j] = U.j.V[n0 + j][k];
            #pragma unroll
            for (int i = 0; i < 4; ++i)
                #pragma unroll
                for (int j = 0; j < 4; ++j) lm[i*4 + j] += vm[i] * vn[j];
        }

        float fa[4];
        #pragma unroll
        for (int o = 0; o < 4; ++o) fa[o] = 0.f;
        #pragma unroll
        for (int i = 0; i < 4; ++i)
            #pragma unroll
            for (int j = 0; j < 4; ++j) {
                int gi = m0 + i, gj = n0 + j;
                if (gi <= gj) {
                    int p = gi*64 - (gi*(gi-1))/2 + (gj - gi);
                    float lv = lm[i*4 + j];
                    #pragma unroll
                    for (int o = 0; o < 4; ++o) fa[o] += lv * fcw[o*2080 + p];
                }
            }

        #pragma unroll
        for (int o = 0; o < 4; ++o)
            for (int off = 32; off > 0; off >>= 1)
                fa[o] += __shfl_down(fa[o], off, 64);
        if (lane == 0) {
            #pragma unroll
            for (int o = 0; o < 4; ++o) wred2[w*4 + o] = fa[o];
        }
    }
    __syncthreads();
    if (tid < 4)
        out[b*4 + tid] = wred2[tid] + wred2[4 + tid] + wred2[8 + tid]
                       + wred2[12 + tid] + fcb[tid];
}

// ---------------------------------------------------------------------------
extern "C" void kernel_launch(void* const* d_in, const int* in_sizes, int n_in,
                              void* d_out, int out_size, void* d_ws, size_t ws_size,
                              hipStream_t stream) {
    (void)in_sizes; (void)n_in; (void)out_size; (void)ws_size;
    const float* x   = (const float*)d_in[0];
    const float* ws0 = (const float*)d_in[1];
    const float* ws1 = (const float*)d_in[2];
    const float* ws2 = (const float*)d_in[3];
    const float* bsg = (const float*)d_in[4];
    const float* bsb = (const float*)d_in[5];
    const float* bsm = (const float*)d_in[6];
    const float* bsv = (const float*)d_in[7];
    const float* wf  = (const float*)d_in[8];
    const float* bfg = (const float*)d_in[9];
    const float* bfb = (const float*)d_in[10];
    const float* bfm = (const float*)d_in[11];
    const float* bfv = (const float*)d_in[12];
    const float* wt0 = (const float*)d_in[13];
    const float* wt1 = (const float*)d_in[14];
    const float* wt2 = (const float*)d_in[15];
    const float* btg = (const float*)d_in[16];
    const float* btb = (const float*)d_in[17];
    const float* btm = (const float*)d_in[18];
    const float* btv = (const float*)d_in[19];
    const float* Wm  = (const float*)d_in[20];
    const float* fcw = (const float*)d_in[21];
    const float* fcb = (const float*)d_in[22];

    float* wsf   = (float*)d_ws;
    float* yb    = wsf + WS_Y;
    float* hpart = wsf + WS_HPART;

    k_prep<<<9, 64, 0, stream>>>(ws0, ws1, ws2, bsg, bsb, bsm, bsv,
                                 wf, bfg, bfb, bfm, bfv,
                                 wt0, wt1, wt2, btg, btb, btm, btv, wsf);
    k_main<<<512, 256, 0, stream>>>(x, wsf, Wm, yb, hpart);
    k_eig<<<128, 1024, 0, stream>>>(yb, hpart, fcw, fcb, (float*)d_out);
}

// Round 21
// 596.637 us; speedup vs baseline: 1.1654x; 1.1654x over previous
//
#include <hip/hip_runtime.h>
#include <math.h>

// ---------------------------------------------------------------------------
// STaRNet forward, fully fused fp32 pipeline.  (R19 measured-best revert.)
//
//  k_prep : 9 small blocks (8 tap-blocks + 1 M-fold) - parallel param fold.
//  k_main : R13 structure (measured ~245us; pk_fma/uniptr/2-t all regressed):
//           2-phase g-split, xt[25][320] (31.25KB, 5 blocks/CU), v4f conv +
//           y-accum, accumulators in registers.
//  k_eig  : R12 structure, NSWEEP 4 (absmax 2^-7 = 82% of threshold).
//           Jacobi at 97% of CU LDS-issue bound -> structurally done.
// ---------------------------------------------------------------------------

typedef __attribute__((ext_vector_type(4))) float v4f;

#define NSWEEP 4

// ws float offsets
#define WS_M      0         // 50*22
#define WS_BIASF  1100      // 50
#define WS_WTF    1152      // 50*336 compact taps
#define WS_BT     17952     // 450
#define WS_HPART  18432     // 512
#define WS_Y      32768     // 128*64*1001

__global__ void k_prep(
    const float* __restrict__ ws0, const float* __restrict__ ws1, const float* __restrict__ ws2,
    const float* __restrict__ bsg, const float* __restrict__ bsb, const float* __restrict__ bsm, const float* __restrict__ bsv,
    const float* __restrict__ wf,
    const float* __restrict__ bfg, const float* __restrict__ bfb, const float* __restrict__ bfm, const float* __restrict__ bfv,
    const float* __restrict__ wt0, const float* __restrict__ wt1, const float* __restrict__ wt2,
    const float* __restrict__ btg, const float* __restrict__ btb, const float* __restrict__ btm, const float* __restrict__ btv,
    float* __restrict__ wsf)
{
    int tid = threadIdx.x;
    int blk = blockIdx.x;
    if (blk < 8) {
        int c = blk * 64 + tid;   // 8 blocks x 64 threads cover 450 channels
        if (c < 450) {
            int i = c / 150, o = c % 150;
            int g = o / 3,   jr = o % 3;
            int k = (i == 0) ? 64 : ((i == 1) ? 32 : 16);
            float ga = btg[i*150 + o], bb = btb[i*150 + o];
            float mm = btm[i*150 + o], vv = btv[i*150 + o];
            float s = ga * rsqrtf(vv + 1e-5f);
            wsf[WS_BT + c] = bb - s * mm;
            int base = g*336 + ((i == 0) ? jr*64 : (i == 1) ? 192 + jr*32 : 288 + jr*16);
            const float* wsrc = (i == 0) ? wt0 : ((i == 1) ? wt1 : wt2);
            float* dst = wsf + WS_WTF + base;
            for (int t = 0; t < k; ++t) dst[t] = s * wsrc[o*k + t];
        }
    } else {
        if (tid < 50) {
            int f = tid;
            float sf = bfg[f] * rsqrtf(bfv[f] + 1e-5f);
            float row[22];
            for (int c = 0; c < 22; ++c) row[c] = 0.f;
            float bacc = 0.f;
            for (int j = 0; j < 60; ++j) {
                int i, k, j0; const float* wsp;
                if (j < 22)      { i = 0; k = 1; j0 = j;      wsp = ws0; }
                else if (j < 42) { i = 1; k = 3; j0 = j - 22; wsp = ws1; }
                else             { i = 2; k = 5; j0 = j - 42; wsp = ws2; }
                float si = bsg[i] * rsqrtf(bsv[i] + 1e-5f);
                float bi = bsb[i] - si * bsm[i];
                float wfj = wf[f*60 + j];
                for (int d = 0; d < k; ++d) row[j0 + d] += wfj * si * wsp[d];
                bacc += wfj * bi;
            }
            for (int c = 0; c < 22; ++c) wsf[WS_M + f*22 + c] = sf * row[c];
            wsf[WS_BIASF + f] = sf * (bacc - bfm[f]) + bfb[f];
        }
    }
}

// ---------------------------------------------------------------------------
__global__ __launch_bounds__(256) void k_main(
    const float* __restrict__ x, const float* __restrict__ wsf,
    const float* __restrict__ Wmap, float* __restrict__ y,
    float* __restrict__ hpart)
{
    const int b    = blockIdx.x >> 2;
    const int tile = blockIdx.x & 3;
    const int t0   = tile * 256;
    const int tid  = threadIdx.x;

    __shared__ float xt[25][320];   // xf half-tile (31.25 KB -> 5 blocks/CU)
    __shared__ float wred[4];

    const float* Mg    = wsf + WS_M;
    const float* biasf = wsf + WS_BIASF;
    const float* wtf   = wsf + WS_WTF;
    const float* bt    = wsf + WS_BT;

    const int t = t0 + tid;
    const bool act = (t <= 1000);
    v4f yv4[16];
    #pragma unroll
    for (int m = 0; m < 16; ++m) yv4[m] = (v4f){0.f, 0.f, 0.f, 0.f};
    float hsq = 0.f;

    for (int ph = 0; ph < 2; ++ph) {
        const int gbase = 25 * ph;
        if (ph) __syncthreads();   // prev-phase conv reads done before restage

        // ---- stage xf rows [gbase, gbase+25) ----
        for (int col = tid; col < 320; col += 256) {
            int tx = t0 + col - 32;
            if (tx >= 0 && tx < 1000) {
                float xv[22];
                #pragma unroll
                for (int c = 0; c < 22; ++c) xv[c] = x[(b*22 + c)*1000 + tx];
                for (int gl = 0; gl < 25; ++gl) {
                    int g = gbase + gl;
                    float a = biasf[g];
                    #pragma unroll
                    for (int c = 0; c < 22; ++c) a += Mg[g*22 + c] * xv[c];
                    xt[gl][col] = a;
                }
            } else {
                for (int gl = 0; gl < 25; ++gl) xt[gl][col] = 0.f;
            }
        }
        __syncthreads();

        // ---- conv + y-accum for these 25 g ----
        if (act) {
            for (int gl = 0; gl < 25; ++gl) {
                const int g = gbase + gl;
                const float* xb = &xt[gl][tid];
                const float* wg = wtf + g * 336;
                v4f h4[9];
                #pragma unroll
                for (int j = 0; j < 9; ++j) h4[j] = (v4f){0.f, 0.f, 0.f, 0.f};
                #pragma unroll
                for (int tau = 0; tau < 64; tau += 4) {
                    v4f xv = (v4f){xb[tau], xb[tau+1], xb[tau+2], xb[tau+3]};
                    h4[0] += (*(const v4f*)(wg + tau))       * xv;
                    h4[1] += (*(const v4f*)(wg + 64 + tau))  * xv;
                    h4[2] += (*(const v4f*)(wg + 128 + tau)) * xv;
                    if (tau >= 16 && tau < 48) {
                        int u = tau - 16;
                        h4[3] += (*(const v4f*)(wg + 192 + u)) * xv;
                        h4[4] += (*(const v4f*)(wg + 224 + u)) * xv;
                        h4[5] += (*(const v4f*)(wg + 256 + u)) * xv;
                    }
                    if (tau >= 24 && tau < 40) {
                        int u = tau - 24;
                        h4[6] += (*(const v4f*)(wg + 288 + u)) * xv;
                        h4[7] += (*(const v4f*)(wg + 304 + u)) * xv;
                        h4[8] += (*(const v4f*)(wg + 320 + u)) * xv;
                    }
                }
                #pragma unroll
                for (int j = 0; j < 9; ++j) {
                    int c = (j < 3) ? (3*g + j)
                          : (j < 6) ? (150 + 3*g + (j - 3))
                                    : (300 + 3*g + (j - 6));
                    float hv = (h4[j].x + h4[j].y) + (h4[j].z + h4[j].w) + bt[c];
                    hsq += hv * hv;
                    const v4f* wr4 = (const v4f*)(Wmap + c * 64);  // wave-uniform
                    v4f hv4 = (v4f){hv, hv, hv, hv};
                    #pragma unroll
                    for (int m = 0; m < 16; ++m) yv4[m] += wr4[m] * hv4;
                }
            }
        }
    }

    if (act) {
        #pragma unroll
        for (int k = 0; k < 16; ++k) {
            y[(b*64 + 4*k)*1001 + t]     = yv4[k].x;
            y[(b*64 + 4*k + 1)*1001 + t] = yv4[k].y;
            y[(b*64 + 4*k + 2)*1001 + t] = yv4[k].z;
            y[(b*64 + 4*k + 3)*1001 + t] = yv4[k].w;
        }
    }

    for (int off = 32; off > 0; off >>= 1) hsq += __shfl_down(hsq, off, 64);
    int wid = tid >> 6, lane = tid & 63;
    if (lane == 0) wred[wid] = hsq;
    __syncthreads();
    if (tid == 0) hpart[blockIdx.x] = wred[0] + wred[1] + wred[2] + wred[3];
}

// ---------------------------------------------------------------------------
// pair schedule: round rr, pair j: j==0 -> (63, rr); else
// p=(rr+j)%63, q=(rr+63-j)%63. All pairs disjoint within a round.
__device__ __forceinline__ void pair_pq(int rr, int j, int& p, int& q) {
    if (j == 0) { p = 63; q = rr; }
    else {
        int a = rr + j;       if (a >= 63) a -= 63;
        int c = rr + 63 - j;  if (c >= 63) c -= 63;
        p = a; q = c;
    }
}

union SMu {
    float yt[64][129];                               // syrk staging (33024 B)
    struct { float A[64][65]; float V[64][65]; } j;  // Jacobi (33280 B)
};

__global__ __launch_bounds__(1024) void k_eig(
    const float* __restrict__ y, const float* __restrict__ hpart,
    const float* __restrict__ fcw, const float* __restrict__ fcb,
    float* __restrict__ out)
{
    const int b    = blockIdx.x;
    const int tid  = threadIdx.x;
    const int w    = tid >> 6;     // wave 0..15
    const int lane = tid & 63;

    __shared__ SMu U;
    __shared__ float le[64];
    __shared__ float wred2[16];

    // ---- syrk: acc = y y^T; staging by all 16 waves, MACs on first 256 ----
    const int mg = tid >> 4, ng = tid & 15;       // valid for tid<256
    const int m0 = mg * 4,  n0 = ng * 4;
    float acc[16];
    #pragma unroll
    for (int i = 0; i < 16; ++i) acc[i] = 0.f;
    for (int tile = 0; tile < 8; ++tile) {
        for (int idx = tid; idx < 64*128; idx += 1024) {
            int row = idx >> 7, col = idx & 127;
            int tg = tile * 128 + col;
            U.yt[row][col] = (tg <= 1000) ? y[(b*64 + row)*1001 + tg] : 0.f;
        }
        __syncthreads();
        if (tid < 256) {
            for (int tt = 0; tt < 128; ++tt) {
                float ym[4], yn[4];
                #pragma unroll
                for (int i = 0; i < 4; ++i) ym[i] = U.yt[m0 + i][tt];
                #pragma unroll
                for (int j = 0; j < 4; ++j) yn[j] = U.yt[n0 + j][tt];
                #pragma unroll
                for (int i = 0; i < 4; ++i)
                    #pragma unroll
                    for (int j = 0; j < 4; ++j) acc[i*4 + j] += ym[i] * yn[j];
            }
        }
        __syncthreads();
    }
    if (tid < 256) {
        float hs = hpart[b*4] + hpart[b*4+1] + hpart[b*4+2] + hpart[b*4+3];
        float mu = hs / (999.f * 450.f);
        #pragma unroll
        for (int i = 0; i < 4; ++i)
            #pragma unroll
            for (int j = 0; j < 4; ++j) {
                int mm = m0 + i, nn = n0 + j;
                U.j.A[mm][nn] = acc[i*4 + j] * (0.95f / 999.f)
                              + ((mm == nn) ? 0.05f * mu : 0.f);
                U.j.V[mm][nn] = (mm == nn) ? 1.f : 0.f;
            }
    }
    __syncthreads();

    // ---- parallel cyclic Jacobi: 16 waves x 2 pairs, conflict-free b32 ----
    for (int sweep = 0; sweep < NSWEEP; ++sweep)
    for (int rr = 0; rr < 63; ++rr) {
        float cp, sp;
        {
            int jj = w + ((lane & 1) << 4);
            int p, q; pair_pq(rr, jj, p, q);
            float app = U.j.A[p][p], aqq = U.j.A[q][q], apq = U.j.A[p][q];
            bool z = (fabsf(apq) <= 1e-30f);
            float apqs = z ? 1.f : apq;
            float tau = (aqq - app) * __builtin_amdgcn_rcpf(2.f * apqs);
            float tt = copysignf(1.f, tau) / (fabsf(tau) + sqrtf(1.f + tau*tau));
            float c = rsqrtf(1.f + tt*tt);
            float s = tt * c;
            cp = z ? 1.f : c;
            sp = z ? 0.f : s;
        }
        float c0 = __shfl(cp, 0, 64), s0 = __shfl(sp, 0, 64);
        float c1 = __shfl(cp, 1, 64), s1 = __shfl(sp, 1, 64);
        int p0, q0, p1, q1;
        pair_pq(rr, w,      p0, q0);
        pair_pq(rr, w + 16, p1, q1);

        // col phase: batched loads, rotate, batched stores (A and V)
        float a0p = U.j.A[lane][p0], a0q = U.j.A[lane][q0];
        float a1p = U.j.A[lane][p1], a1q = U.j.A[lane][q1];
        float v0p = U.j.V[lane][p0], v0q = U.j.V[lane][q0];
        float v1p = U.j.V[lane][p1], v1q = U.j.V[lane][q1];
        U.j.A[lane][p0] = c0*a0p - s0*a0q;
        U.j.A[lane][q0] = s0*a0p + c0*a0q;
        U.j.A[lane][p1] = c1*a1p - s1*a1q;
        U.j.A[lane][q1] = s1*a1p + c1*a1q;
        U.j.V[lane][p0] = c0*v0p - s0*v0q;
        U.j.V[lane][q0] = s0*v0p + c0*v0q;
        U.j.V[lane][p1] = c1*v1p - s1*v1q;
        U.j.V[lane][q1] = s1*v1p + c1*v1q;
        __syncthreads();

        // row phase (A only)
        float r0p = U.j.A[p0][lane], r0q = U.j.A[q0][lane];
        float r1p = U.j.A[p1][lane], r1q = U.j.A[q1][lane];
        U.j.A[p0][lane] = c0*r0p - s0*r0q;
        U.j.A[q0][lane] = s0*r0p + c0*r0q;
        U.j.A[p1][lane] = c1*r1p - s1*r1q;
        U.j.A[q1][lane] = s1*r1p + c1*r1q;
        __syncthreads();
    }

    // ---- log-eig reconstruction + FC (first 256 threads) ----
    if (tid < 64) le[tid] = logf(fmaxf(U.j.A[tid][tid], 1e-6f));
    __syncthreads();

    if (tid < 256) {
        float lm[16];
        #pragma unroll
        for (int i = 0; i < 16; ++i) lm[i] = 0.f;
        for (int k = 0; k < 64; ++k) {
            float l = le[k];
            float vm[4], vn[4];
            #pragma unroll
            for (int i = 0; i < 4; ++i) vm[i] = U.j.V[m0 + i][k] * l;
            #pragma unroll
            for (int j = 0; j < 4; ++j) vn[j] = U.j.V[n0 + j][k];
            #pragma unroll
            for (int i = 0; i < 4; ++i)
                #pragma unroll
                for (int j = 0; j < 4; ++j) lm[i*4 + j] += vm[i] * vn[j];
        }

        float fa[4];
        #pragma unroll
        for (int o = 0; o < 4; ++o) fa[o] = 0.f;
        #pragma unroll
        for (int i = 0; i < 4; ++i)
            #pragma unroll
            for (int j = 0; j < 4; ++j) {
                int gi = m0 + i, gj = n0 + j;
                if (gi <= gj) {
                    int p = gi*64 - (gi*(gi-1))/2 + (gj - gi);
                    float lv = lm[i*4 + j];
                    #pragma unroll
                    for (int o = 0; o < 4; ++o) fa[o] += lv * fcw[o*2080 + p];
                }
            }

        #pragma unroll
        for (int o = 0; o < 4; ++o)
            for (int off = 32; off > 0; off >>= 1)
                fa[o] += __shfl_down(fa[o], off, 64);
        if (lane == 0) {
            #pragma unroll
            for (int o = 0; o < 4; ++o) wred2[w*4 + o] = fa[o];
        }
    }
    __syncthreads();
    if (tid < 4)
        out[b*4 + tid] = wred2[tid] + wred2[4 + tid] + wred2[8 + tid]
                       + wred2[12 + tid] + fcb[tid];
}

// ---------------------------------------------------------------------------
extern "C" void kernel_launch(void* const* d_in, const int* in_sizes, int n_in,
                              void* d_out, int out_size, void* d_ws, size_t ws_size,
                              hipStream_t stream) {
    (void)in_sizes; (void)n_in; (void)out_size; (void)ws_size;
    const float* x   = (const float*)d_in[0];
    const float* ws0 = (const float*)d_in[1];
    const float* ws1 = (const float*)d_in[2];
    const float* ws2 = (const float*)d_in[3];
    const float* bsg = (const float*)d_in[4];
    const float* bsb = (const float*)d_in[5];
    const float* bsm = (const float*)d_in[6];
    const float* bsv = (const float*)d_in[7];
    const float* wf  = (const float*)d_in[8];
    const float* bfg = (const float*)d_in[9];
    const float* bfb = (const float*)d_in[10];
    const float* bfm = (const float*)d_in[11];
    const float* bfv = (const float*)d_in[12];
    const float* wt0 = (const float*)d_in[13];
    const float* wt1 = (const float*)d_in[14];
    const float* wt2 = (const float*)d_in[15];
    const float* btg = (const float*)d_in[16];
    const float* btb = (const float*)d_in[17];
    const float* btm = (const float*)d_in[18];
    const float* btv = (const float*)d_in[19];
    const float* Wm  = (const float*)d_in[20];
    const float* fcw = (const float*)d_in[21];
    const float* fcb = (const float*)d_in[22];

    float* wsf   = (float*)d_ws;
    float* yb    = wsf + WS_Y;
    float* hpart = wsf + WS_HPART;

    k_prep<<<9, 64, 0, stream>>>(ws0, ws1, ws2, bsg, bsb, bsm, bsv,
                                 wf, bfg, bfb, bfm, bfv,
                                 wt0, wt1, wt2, btg, btb, btm, btv, wsf);
    k_main<<<512, 256, 0, stream>>>(x, wsf, Wm, yb, hpart);
    k_eig<<<128, 1024, 0, stream>>>(yb, hpart, fcw, fcb, (float*)d_out);
}